// Round 2
// baseline (88.148 us; speedup 1.0000x reference)
//
#include <hip/hip_runtime.h>
#include <stdint.h>

// KumaMask: z = clip(Kumaraswamy-rsample stretch, 0, 1)
//   a = softplus(x·Wa + ba); b = softplus(x·Wb + bb)
//   u = jax.random.uniform(key(42), [B*T,1])  — threefry2x32, PARTITIONABLE
//     stream (JAX >= 0.4.36 default): counter = (hi,lo) = (0, i),
//     bits = out0 ^ out1  (for 32-bit widths)
//   k = (1 - u^(1/b))^(1/a); z = clip(1.2*k - 0.1, 0, 1)
// x: [131072, 512] f32 -> 256 MiB read once => HBM-bound, floor ~43us.

__device__ __forceinline__ uint32_t rotl32(uint32_t v, uint32_t r) {
    return (v << r) | (v >> (32u - r));
}

// threefry2x32-20 with key pair (0, 42)  == jax.random.key(42)
// ks = [0, 42, 0x1BD11BDA ^ 0 ^ 42]
__device__ __forceinline__ void threefry2x32_k042(uint32_t& x0, uint32_t& x1) {
    const uint32_t ks1 = 42u;
    const uint32_t ks2 = 0x1BD11BDAu ^ 42u;
    // initial key injection (x0 += ks0 == 0 elided)
    x1 += ks1;
#define TFR(r) { x0 += x1; x1 = rotl32(x1, (r)); x1 ^= x0; }
    TFR(13u) TFR(15u) TFR(26u) TFR(6u)
    x0 += ks1; x1 += ks2 + 1u;
    TFR(17u) TFR(29u) TFR(16u) TFR(24u)
    x0 += ks2; x1 += 2u;                       // + ks0 + 2
    TFR(13u) TFR(15u) TFR(26u) TFR(6u)
    /* x0 += ks0 */ x1 += ks1 + 3u;
    TFR(17u) TFR(29u) TFR(16u) TFR(24u)
    x0 += ks1; x1 += ks2 + 4u;
    TFR(13u) TFR(15u) TFR(26u) TFR(6u)
    x0 += ks2; x1 += 5u;                       // + ks0 + 5
#undef TFR
}

// jax.nn.softplus = logaddexp(v, 0) = max(v,0) + log1p(exp(-|v|))
__device__ __forceinline__ float softplus_f(float v) {
    return fmaxf(v, 0.0f) + log1pf(expf(-fabsf(v)));
}

__global__ __launch_bounds__(256) void kuma_mask_kernel(
    const float* __restrict__ x,
    const float* __restrict__ Wa, const float* __restrict__ ba,
    const float* __restrict__ Wb, const float* __restrict__ bb,
    float* __restrict__ out, int nrows)
{
    const int lane = threadIdx.x & 63;
    const int wid  = (int)((blockIdx.x * blockDim.x + threadIdx.x) >> 6);
    const int nw   = (int)((gridDim.x * blockDim.x) >> 6);

    // Per-lane weight fragments (read once; L2-cached broadcast, 4 KiB total)
    const float4 wa0 = *reinterpret_cast<const float4*>(Wa + 4 * lane);
    const float4 wa1 = *reinterpret_cast<const float4*>(Wa + 256 + 4 * lane);
    const float4 wb0 = *reinterpret_cast<const float4*>(Wb + 4 * lane);
    const float4 wb1 = *reinterpret_cast<const float4*>(Wb + 256 + 4 * lane);
    const float ba_s = ba[0];
    const float bb_s = bb[0];

    for (int row = wid; row < nrows; row += nw) {
        const float* xr = x + (size_t)row * 512;
        // Two coalesced float4 loads per lane: wave covers the full 2 KiB row.
        const float4 v0 = *reinterpret_cast<const float4*>(xr + 4 * lane);
        const float4 v1 = *reinterpret_cast<const float4*>(xr + 256 + 4 * lane);

        float pa;
        pa = v0.x * wa0.x;
        pa = fmaf(v0.y, wa0.y, pa);
        pa = fmaf(v0.z, wa0.z, pa);
        pa = fmaf(v0.w, wa0.w, pa);
        pa = fmaf(v1.x, wa1.x, pa);
        pa = fmaf(v1.y, wa1.y, pa);
        pa = fmaf(v1.z, wa1.z, pa);
        pa = fmaf(v1.w, wa1.w, pa);

        float pb;
        pb = v0.x * wb0.x;
        pb = fmaf(v0.y, wb0.y, pb);
        pb = fmaf(v0.z, wb0.z, pb);
        pb = fmaf(v0.w, wb0.w, pb);
        pb = fmaf(v1.x, wb1.x, pb);
        pb = fmaf(v1.y, wb1.y, pb);
        pb = fmaf(v1.z, wb1.z, pb);
        pb = fmaf(v1.w, wb1.w, pb);

        // 64-lane butterfly reduction for both dots
        #pragma unroll
        for (int m = 32; m > 0; m >>= 1) {
            pa += __shfl_xor(pa, m, 64);
            pb += __shfl_xor(pb, m, 64);
        }

        // Uniform epilogue on all lanes (no divergence); lane 0 stores.
        const float a = softplus_f(pa + ba_s);
        const float b = softplus_f(pb + bb_s);

        // u: partitionable threefry stream. 64-bit flat index -> (hi,lo)=(0,row);
        // 32-bit bits = out0 ^ out1.
        uint32_t t0 = 0u;
        uint32_t t1 = (uint32_t)row;
        threefry2x32_k042(t0, t1);
        const uint32_t bits = t0 ^ t1;
        const float f = __uint_as_float((bits >> 9) | 0x3f800000u) - 1.0f;
        const float u = fmaxf(f, 1.17549435e-38f);   // max(floats*(1-tiny)+tiny, tiny)

        // k = (1 - u^(1/b))^(1/a)
        const float p     = expf(logf(u) / b);       // u^(1/b), p in (0, 1]
        const float one_m = 1.0f - p;                // >= 0
        const float k     = expf(logf(one_m) / a);   // log(0) = -inf -> k = 0, no NaN
        // stretch to [-0.1, 1.1] then hard clamp to [0, 1]
        const float z = fminf(fmaxf(fmaf(k, 1.2f, -0.1f), 0.0f), 1.0f);

        if (lane == 0) out[row] = z;
    }
}

extern "C" void kernel_launch(void* const* d_in, const int* in_sizes, int n_in,
                              void* d_out, int out_size, void* d_ws, size_t ws_size,
                              hipStream_t stream) {
    const float* x  = (const float*)d_in[0];
    const float* Wa = (const float*)d_in[1];
    const float* ba = (const float*)d_in[2];
    const float* Wb = (const float*)d_in[3];
    const float* bb = (const float*)d_in[4];
    float* out = (float*)d_out;

    const int nrows = in_sizes[0] / 512;   // 131072

    const int block = 256;                  // 4 waves/block
    const int grid  = 2048;                 // 8192 waves, 16 rows each (grid-stride)
    kuma_mask_kernel<<<grid, block, 0, stream>>>(x, Wa, ba, Wb, bb, out, nrows);
}

// Round 3
// 50.615 us; speedup vs baseline: 1.7415x; 1.7415x over previous
//
#include <hip/hip_runtime.h>
#include <stdint.h>

// KumaMask: z = clip(Kumaraswamy-rsample stretch, 0, 1)
//   a = softplus(x·Wa + ba); b = softplus(x·Wb + bb)
//   u = jax.random.uniform(key(42)) — threefry2x32 PARTITIONABLE stream
//     (counter = (0, i), bits = out0 ^ out1)  [verified R2: absmax 1.95e-3]
//   k = (1 - u^(1/b))^(1/a); z = clip(1.2*k - 0.1, 0, 1)
//
// R3 structure: 32-row tile per wave. Coalesced wave-wide row loads +
// butterfly reduce (unchanged), but the sum for row r is CAPTURED into lane r
// (v_cndmask); the expensive epilogue (threefry + 4 transcendental chains)
// runs ONCE per tile with lane l owning row base+l -> 64x less epilogue issue
// than R2's per-row-all-lanes version. 4-row unroll gives 8 KiB of loads in
// flight per wave. Grid 1024x256 = 4096 waves = 4/SIMD.

__device__ __forceinline__ uint32_t rotl32(uint32_t v, uint32_t r) {
    return (v << r) | (v >> (32u - r));
}

// threefry2x32-20 with key pair (0, 42) == jax.random.key(42)
__device__ __forceinline__ void threefry2x32_k042(uint32_t& x0, uint32_t& x1) {
    const uint32_t ks1 = 42u;
    const uint32_t ks2 = 0x1BD11BDAu ^ 42u;
    x1 += ks1;                                 // x0 += ks0 (=0) elided
#define TFR(r) { x0 += x1; x1 = rotl32(x1, (r)); x1 ^= x0; }
    TFR(13u) TFR(15u) TFR(26u) TFR(6u)
    x0 += ks1; x1 += ks2 + 1u;
    TFR(17u) TFR(29u) TFR(16u) TFR(24u)
    x0 += ks2; x1 += 2u;
    TFR(13u) TFR(15u) TFR(26u) TFR(6u)
    x1 += ks1 + 3u;
    TFR(17u) TFR(29u) TFR(16u) TFR(24u)
    x0 += ks1; x1 += ks2 + 4u;
    TFR(13u) TFR(15u) TFR(26u) TFR(6u)
    x0 += ks2; x1 += 5u;
#undef TFR
}

__device__ __forceinline__ float softplus_f(float v) {
    return fmaxf(v, 0.0f) + log1pf(expf(-fabsf(v)));
}

__global__ __launch_bounds__(256) void kuma_mask_kernel(
    const float* __restrict__ x,
    const float* __restrict__ Wa, const float* __restrict__ ba,
    const float* __restrict__ Wb, const float* __restrict__ bb,
    float* __restrict__ out, int nrows)
{
    const int lane = threadIdx.x & 63;
    const int wid  = (int)((blockIdx.x * blockDim.x + threadIdx.x) >> 6);
    const int nw   = (int)((gridDim.x * blockDim.x) >> 6);

    // Per-lane weight fragments (4 KiB total, L2-resident)
    const float4 wa0 = *reinterpret_cast<const float4*>(Wa + 4 * lane);
    const float4 wa1 = *reinterpret_cast<const float4*>(Wa + 256 + 4 * lane);
    const float4 wb0 = *reinterpret_cast<const float4*>(Wb + 4 * lane);
    const float4 wb1 = *reinterpret_cast<const float4*>(Wb + 256 + 4 * lane);
    const float ba_s = ba[0];
    const float bb_s = bb[0];

    const int ntiles = nrows >> 5;             // 32 rows per tile

    for (int tile = wid; tile < ntiles; tile += nw) {
        const int rowbase = tile << 5;
        float spa = 0.0f, spb = 0.0f;          // lane l captures row rowbase+l

        #pragma unroll
        for (int rr = 0; rr < 32; rr += 4) {
            // Issue all 8 loads (4 rows x 2 KiB, coalesced) before any use.
            float4 v0_0, v1_0, v0_1, v1_1, v0_2, v1_2, v0_3, v1_3;
            {
                const float* xr0 = x + (size_t)(rowbase + rr + 0) * 512;
                const float* xr1 = x + (size_t)(rowbase + rr + 1) * 512;
                const float* xr2 = x + (size_t)(rowbase + rr + 2) * 512;
                const float* xr3 = x + (size_t)(rowbase + rr + 3) * 512;
                v0_0 = *reinterpret_cast<const float4*>(xr0 + 4 * lane);
                v1_0 = *reinterpret_cast<const float4*>(xr0 + 256 + 4 * lane);
                v0_1 = *reinterpret_cast<const float4*>(xr1 + 4 * lane);
                v1_1 = *reinterpret_cast<const float4*>(xr1 + 256 + 4 * lane);
                v0_2 = *reinterpret_cast<const float4*>(xr2 + 4 * lane);
                v1_2 = *reinterpret_cast<const float4*>(xr2 + 256 + 4 * lane);
                v0_3 = *reinterpret_cast<const float4*>(xr3 + 4 * lane);
                v1_3 = *reinterpret_cast<const float4*>(xr3 + 256 + 4 * lane);
            }

#define ROW_REDUCE(V0, V1, Q)                                              \
            {                                                              \
                float pa = (V0).x * wa0.x;                                 \
                pa = fmaf((V0).y, wa0.y, pa);                              \
                pa = fmaf((V0).z, wa0.z, pa);                              \
                pa = fmaf((V0).w, wa0.w, pa);                              \
                pa = fmaf((V1).x, wa1.x, pa);                              \
                pa = fmaf((V1).y, wa1.y, pa);                              \
                pa = fmaf((V1).z, wa1.z, pa);                              \
                pa = fmaf((V1).w, wa1.w, pa);                              \
                float pb = (V0).x * wb0.x;                                 \
                pb = fmaf((V0).y, wb0.y, pb);                              \
                pb = fmaf((V0).z, wb0.z, pb);                              \
                pb = fmaf((V0).w, wb0.w, pb);                              \
                pb = fmaf((V1).x, wb1.x, pb);                              \
                pb = fmaf((V1).y, wb1.y, pb);                              \
                pb = fmaf((V1).z, wb1.z, pb);                              \
                pb = fmaf((V1).w, wb1.w, pb);                              \
                _Pragma("unroll")                                          \
                for (int m = 32; m > 0; m >>= 1) {                         \
                    pa += __shfl_xor(pa, m, 64);                           \
                    pb += __shfl_xor(pb, m, 64);                           \
                }                                                          \
                if (lane == rr + (Q)) { spa = pa; spb = pb; }              \
            }

            ROW_REDUCE(v0_0, v1_0, 0)
            ROW_REDUCE(v0_1, v1_1, 1)
            ROW_REDUCE(v0_2, v1_2, 2)
            ROW_REDUCE(v0_3, v1_3, 3)
#undef ROW_REDUCE
        }

        // ---- Per-lane epilogue: lane l owns row rowbase+l (l < 32) ----
        const float a = softplus_f(spa + ba_s);
        const float b = softplus_f(spb + bb_s);

        // partitionable threefry: counter (hi,lo) = (0, row); bits = o0 ^ o1
        uint32_t t0 = 0u;
        uint32_t t1 = (uint32_t)(rowbase + lane);
        threefry2x32_k042(t0, t1);
        const uint32_t bits = t0 ^ t1;
        const float f = __uint_as_float((bits >> 9) | 0x3f800000u) - 1.0f;
        const float u = fmaxf(f, 1.17549435e-38f);

        const float p     = expf(logf(u) / b);       // u^(1/b) in (0,1]
        const float one_m = 1.0f - p;
        const float k     = expf(logf(one_m) / a);   // log(0)=-inf -> k=0
        const float z = fminf(fmaxf(fmaf(k, 1.2f, -0.1f), 0.0f), 1.0f);

        if (lane < 32) out[rowbase + lane] = z;
    }
}

extern "C" void kernel_launch(void* const* d_in, const int* in_sizes, int n_in,
                              void* d_out, int out_size, void* d_ws, size_t ws_size,
                              hipStream_t stream) {
    const float* x  = (const float*)d_in[0];
    const float* Wa = (const float*)d_in[1];
    const float* ba = (const float*)d_in[2];
    const float* Wb = (const float*)d_in[3];
    const float* bb = (const float*)d_in[4];
    float* out = (float*)d_out;

    const int nrows = in_sizes[0] / 512;   // 131072

    // 4096 wave-tiles of 32 rows; 1024 blocks x 256 thr = 4096 waves (4/SIMD)
    const int block = 256;
    const int grid  = 1024;
    kuma_mask_kernel<<<grid, block, 0, stream>>>(x, Wa, ba, Wb, bb, out, nrows);
}

// Round 4
// 48.350 us; speedup vs baseline: 1.8231x; 1.0468x over previous
//
#include <hip/hip_runtime.h>
#include <stdint.h>

// KumaMask: z = clip(Kumaraswamy-rsample stretch, 0, 1)
//   a = softplus(x·Wa + ba); b = softplus(x·Wb + bb)
//   u = jax.random.uniform(key(42)) — threefry2x32 PARTITIONABLE stream
//     (counter = (0, i), bits = out0 ^ out1)  [verified R2: absmax 1.95e-3]
//   k = (1 - u^(1/b))^(1/a); z = clip(1.2*k - 0.1, 0, 1)
//
// R4: merge-tree reduction. A 32-row tile has 64 lane-reductions to do
// (32 rows x {a,b}) — instead of 64 x 6-step butterflies (384 shuffles),
// a 6-level pairwise merge tree does it in 63 merges (1 shuffle each) and
// leaves pa(row l) in lane l, pb(row l) in lane l^32. One extra shfl_xor(32)
// pairs them. DS-pipe ops per tile: 384 -> 64. Loads and per-lane epilogue
// (once per tile) unchanged from R3 (50.6us, 5.3 TB/s).

__device__ __forceinline__ uint32_t rotl32(uint32_t v, uint32_t r) {
    return (v << r) | (v >> (32u - r));
}

// threefry2x32-20 with key pair (0, 42) == jax.random.key(42)
__device__ __forceinline__ void threefry2x32_k042(uint32_t& x0, uint32_t& x1) {
    const uint32_t ks1 = 42u;
    const uint32_t ks2 = 0x1BD11BDAu ^ 42u;
    x1 += ks1;                                 // x0 += ks0 (=0) elided
#define TFR(r) { x0 += x1; x1 = rotl32(x1, (r)); x1 ^= x0; }
    TFR(13u) TFR(15u) TFR(26u) TFR(6u)
    x0 += ks1; x1 += ks2 + 1u;
    TFR(17u) TFR(29u) TFR(16u) TFR(24u)
    x0 += ks2; x1 += 2u;
    TFR(13u) TFR(15u) TFR(26u) TFR(6u)
    x1 += ks1 + 3u;
    TFR(17u) TFR(29u) TFR(16u) TFR(24u)
    x0 += ks1; x1 += ks2 + 4u;
    TFR(13u) TFR(15u) TFR(26u) TFR(6u)
    x0 += ks2; x1 += 5u;
#undef TFR
}

__device__ __forceinline__ float softplus_f(float v) {
    return fmaxf(v, 0.0f) + log1pf(expf(-fabsf(v)));
}

// merge two lane-distributed partial sums: returns u-sum in lanes with
// (lane & m) == 0, v-sum in lanes with (lane & m) != 0.
__device__ __forceinline__ float merge_red(float u, float v, int m, int lane) {
    const float s = (lane & m) ? u : v;        // send partner what IT keeps
    const float r = __shfl_xor(s, m, 64);
    return ((lane & m) ? v : u) + r;
}

__device__ __forceinline__ float dot8(const float4& v0, const float4& v1,
                                      const float4& w0, const float4& w1) {
    float p = v0.x * w0.x;
    p = fmaf(v0.y, w0.y, p);
    p = fmaf(v0.z, w0.z, p);
    p = fmaf(v0.w, w0.w, p);
    p = fmaf(v1.x, w1.x, p);
    p = fmaf(v1.y, w1.y, p);
    p = fmaf(v1.z, w1.z, p);
    p = fmaf(v1.w, w1.w, p);
    return p;
}

__global__ __launch_bounds__(256) void kuma_mask_kernel(
    const float* __restrict__ x,
    const float* __restrict__ Wa, const float* __restrict__ ba,
    const float* __restrict__ Wb, const float* __restrict__ bb,
    float* __restrict__ out, int nrows)
{
    const int lane = threadIdx.x & 63;
    const int wid  = (int)((blockIdx.x * blockDim.x + threadIdx.x) >> 6);
    const int nw   = (int)((gridDim.x * blockDim.x) >> 6);

    // Per-lane weight fragments (4 KiB total, L2-resident)
    const float4 wa0 = *reinterpret_cast<const float4*>(Wa + 4 * lane);
    const float4 wa1 = *reinterpret_cast<const float4*>(Wa + 256 + 4 * lane);
    const float4 wb0 = *reinterpret_cast<const float4*>(Wb + 4 * lane);
    const float4 wb1 = *reinterpret_cast<const float4*>(Wb + 256 + 4 * lane);
    const float ba_s = ba[0];
    const float bb_s = bb[0];

    const int ntiles = nrows >> 5;             // 32 rows per tile

    for (int tile = wid; tile < ntiles; tile += nw) {
        const int rowbase = tile << 5;

        // Per-quad (4 rows): dots + merge levels 1,2 -> A[g], B[g] where
        // lane bits[1:0] index the row within the quad.
        float A[8], B[8];
        #pragma unroll
        for (int g = 0; g < 8; ++g) {
            const float* xr = x + (size_t)(rowbase + 4 * g) * 512 + 4 * lane;
            // 8 coalesced float4 loads (4 rows x 2 KiB) issued before use
            const float4 v00 = *reinterpret_cast<const float4*>(xr);
            const float4 v01 = *reinterpret_cast<const float4*>(xr + 256);
            const float4 v10 = *reinterpret_cast<const float4*>(xr + 512);
            const float4 v11 = *reinterpret_cast<const float4*>(xr + 768);
            const float4 v20 = *reinterpret_cast<const float4*>(xr + 1024);
            const float4 v21 = *reinterpret_cast<const float4*>(xr + 1280);
            const float4 v30 = *reinterpret_cast<const float4*>(xr + 1536);
            const float4 v31 = *reinterpret_cast<const float4*>(xr + 1792);

            const float pa0 = dot8(v00, v01, wa0, wa1);
            const float pb0 = dot8(v00, v01, wb0, wb1);
            const float pa1 = dot8(v10, v11, wa0, wa1);
            const float pb1 = dot8(v10, v11, wb0, wb1);
            const float pa2 = dot8(v20, v21, wa0, wa1);
            const float pb2 = dot8(v20, v21, wb0, wb1);
            const float pa3 = dot8(v30, v31, wa0, wa1);
            const float pb3 = dot8(v30, v31, wb0, wb1);

            const float a01 = merge_red(pa0, pa1, 1, lane);
            const float a23 = merge_red(pa2, pa3, 1, lane);
            const float b01 = merge_red(pb0, pb1, 1, lane);
            const float b23 = merge_red(pb2, pb3, 1, lane);
            A[g] = merge_red(a01, a23, 2, lane);   // lane bit1 = row bit1
            B[g] = merge_red(b01, b23, 2, lane);
        }

        // Levels 3..5: lane bits[4:2] = quad index bits
        float A4[4], B4[4];
        #pragma unroll
        for (int i = 0; i < 4; ++i) {
            A4[i] = merge_red(A[2 * i], A[2 * i + 1], 4, lane);
            B4[i] = merge_red(B[2 * i], B[2 * i + 1], 4, lane);
        }
        float A8[2], B8[2];
        #pragma unroll
        for (int i = 0; i < 2; ++i) {
            A8[i] = merge_red(A4[2 * i], A4[2 * i + 1], 8, lane);
            B8[i] = merge_red(B4[2 * i], B4[2 * i + 1], 8, lane);
        }
        const float A16 = merge_red(A8[0], A8[1], 16, lane);
        const float B16 = merge_red(B8[0], B8[1], 16, lane);
        // Level 6: a-class vs b-class -> lane bit5 = param
        const float fin = merge_red(A16, B16, 32, lane);
        const float oth = __shfl_xor(fin, 32, 64);
        const float spa = (lane < 32) ? fin : oth;   // pa(rowbase + (lane&31))
        const float spb = (lane < 32) ? oth : fin;   // pb(rowbase + (lane&31))

        // ---- Epilogue, once per tile; lane l handles row rowbase+(l&31) ----
        const float a = softplus_f(spa + ba_s);
        const float b = softplus_f(spb + bb_s);

        uint32_t t0 = 0u;
        uint32_t t1 = (uint32_t)(rowbase + (lane & 31));
        threefry2x32_k042(t0, t1);
        const uint32_t bits = t0 ^ t1;
        const float f = __uint_as_float((bits >> 9) | 0x3f800000u) - 1.0f;
        const float u = fmaxf(f, 1.17549435e-38f);

        const float p     = expf(logf(u) / b);       // u^(1/b) in (0,1]
        const float one_m = 1.0f - p;
        const float k     = expf(logf(one_m) / a);   // log(0)=-inf -> k=0
        const float z = fminf(fmaxf(fmaf(k, 1.2f, -0.1f), 0.0f), 1.0f);

        if (lane < 32) out[rowbase + lane] = z;
    }
}

extern "C" void kernel_launch(void* const* d_in, const int* in_sizes, int n_in,
                              void* d_out, int out_size, void* d_ws, size_t ws_size,
                              hipStream_t stream) {
    const float* x  = (const float*)d_in[0];
    const float* Wa = (const float*)d_in[1];
    const float* ba = (const float*)d_in[2];
    const float* Wb = (const float*)d_in[3];
    const float* bb = (const float*)d_in[4];
    float* out = (float*)d_out;

    const int nrows = in_sizes[0] / 512;   // 131072

    // 4096 tiles of 32 rows; 1024 blocks x 256 thr = 4096 waves, 1 tile each
    const int block = 256;
    const int grid  = 1024;
    kuma_mask_kernel<<<grid, block, 0, stream>>>(x, Wa, ba, Wb, bb, out, nrows);
}

// Round 5
// 43.622 us; speedup vs baseline: 2.0207x; 1.1084x over previous
//
#include <hip/hip_runtime.h>
#include <stdint.h>

// KumaMask: z = clip(Kumaraswamy-rsample stretch, 0, 1)
//   a = softplus(x·Wa + ba); b = softplus(x·Wb + bb)
//   u = jax.random.uniform(key(42)) — threefry2x32 PARTITIONABLE stream
//     (counter = (0, i), bits = out0 ^ out1)  [verified R2: absmax 1.95e-3]
//   k = (1 - u^(1/b))^(1/a); z = clip(1.2*k - 0.1, 0, 1)
//
// R5: latency-bound fix. R4 analysis: VALU issue ~5us, DS ~2.5us, yet we sit
// 10us over the ~38us read floor -> outstanding-load capacity (Little's law:
// need ~8KB/CU in flight, had ~4KB). Halve tile to 16 rows/wave and double
// the grid: 8192 waves (8/SIMD requested); smaller live state (A[4]/B[4])
// drops VGPR so real occupancy rises -> more loads in flight.
// Tree for 32 values (16 rows x {a,b}): 31 merges + 1 butterfly(32) +
// 1 pairing shfl(16); row = lane&15, param = lane bit4.

__device__ __forceinline__ uint32_t rotl32(uint32_t v, uint32_t r) {
    return (v << r) | (v >> (32u - r));
}

// threefry2x32-20 with key pair (0, 42) == jax.random.key(42)
__device__ __forceinline__ void threefry2x32_k042(uint32_t& x0, uint32_t& x1) {
    const uint32_t ks1 = 42u;
    const uint32_t ks2 = 0x1BD11BDAu ^ 42u;
    x1 += ks1;                                 // x0 += ks0 (=0) elided
#define TFR(r) { x0 += x1; x1 = rotl32(x1, (r)); x1 ^= x0; }
    TFR(13u) TFR(15u) TFR(26u) TFR(6u)
    x0 += ks1; x1 += ks2 + 1u;
    TFR(17u) TFR(29u) TFR(16u) TFR(24u)
    x0 += ks2; x1 += 2u;
    TFR(13u) TFR(15u) TFR(26u) TFR(6u)
    x1 += ks1 + 3u;
    TFR(17u) TFR(29u) TFR(16u) TFR(24u)
    x0 += ks1; x1 += ks2 + 4u;
    TFR(13u) TFR(15u) TFR(26u) TFR(6u)
    x0 += ks2; x1 += 5u;
#undef TFR
}

__device__ __forceinline__ float softplus_f(float v) {
    return fmaxf(v, 0.0f) + log1pf(expf(-fabsf(v)));
}

// merge two lane-distributed partial sums: after this, lanes with
// (lane & m) == 0 hold the u-sum over the lane pair, others the v-sum.
__device__ __forceinline__ float merge_red(float u, float v, int m, int lane) {
    const float s = (lane & m) ? u : v;        // send partner what IT keeps
    const float r = __shfl_xor(s, m, 64);
    return ((lane & m) ? v : u) + r;
}

__device__ __forceinline__ float dot8(const float4& v0, const float4& v1,
                                      const float4& w0, const float4& w1) {
    float p = v0.x * w0.x;
    p = fmaf(v0.y, w0.y, p);
    p = fmaf(v0.z, w0.z, p);
    p = fmaf(v0.w, w0.w, p);
    p = fmaf(v1.x, w1.x, p);
    p = fmaf(v1.y, w1.y, p);
    p = fmaf(v1.z, w1.z, p);
    p = fmaf(v1.w, w1.w, p);
    return p;
}

__global__ __launch_bounds__(256) void kuma_mask_kernel(
    const float* __restrict__ x,
    const float* __restrict__ Wa, const float* __restrict__ ba,
    const float* __restrict__ Wb, const float* __restrict__ bb,
    float* __restrict__ out, int nrows)
{
    const int lane = threadIdx.x & 63;
    const int wid  = (int)((blockIdx.x * blockDim.x + threadIdx.x) >> 6);
    const int nw   = (int)((gridDim.x * blockDim.x) >> 6);

    // Per-lane weight fragments (4 KiB total, L2-resident)
    const float4 wa0 = *reinterpret_cast<const float4*>(Wa + 4 * lane);
    const float4 wa1 = *reinterpret_cast<const float4*>(Wa + 256 + 4 * lane);
    const float4 wb0 = *reinterpret_cast<const float4*>(Wb + 4 * lane);
    const float4 wb1 = *reinterpret_cast<const float4*>(Wb + 256 + 4 * lane);
    const float ba_s = ba[0];
    const float bb_s = bb[0];

    const int ntiles = nrows >> 4;             // 16 rows per tile

    for (int tile = wid; tile < ntiles; tile += nw) {
        const int rowbase = tile << 4;

        // Per-quad (4 rows): dots + merge levels 1,2 -> A[g], B[g];
        // lane bits[1:0] = row-within-quad after these levels.
        float A[4], B[4];
        #pragma unroll
        for (int g = 0; g < 4; ++g) {
            const float* xr = x + (size_t)(rowbase + 4 * g) * 512 + 4 * lane;
            const float4 v00 = *reinterpret_cast<const float4*>(xr);
            const float4 v01 = *reinterpret_cast<const float4*>(xr + 256);
            const float4 v10 = *reinterpret_cast<const float4*>(xr + 512);
            const float4 v11 = *reinterpret_cast<const float4*>(xr + 768);
            const float4 v20 = *reinterpret_cast<const float4*>(xr + 1024);
            const float4 v21 = *reinterpret_cast<const float4*>(xr + 1280);
            const float4 v30 = *reinterpret_cast<const float4*>(xr + 1536);
            const float4 v31 = *reinterpret_cast<const float4*>(xr + 1792);

            const float pa0 = dot8(v00, v01, wa0, wa1);
            const float pb0 = dot8(v00, v01, wb0, wb1);
            const float pa1 = dot8(v10, v11, wa0, wa1);
            const float pb1 = dot8(v10, v11, wb0, wb1);
            const float pa2 = dot8(v20, v21, wa0, wa1);
            const float pb2 = dot8(v20, v21, wb0, wb1);
            const float pa3 = dot8(v30, v31, wa0, wa1);
            const float pb3 = dot8(v30, v31, wb0, wb1);

            const float a01 = merge_red(pa0, pa1, 1, lane);
            const float a23 = merge_red(pa2, pa3, 1, lane);
            const float b01 = merge_red(pb0, pb1, 1, lane);
            const float b23 = merge_red(pb2, pb3, 1, lane);
            A[g] = merge_red(a01, a23, 2, lane);   // lane bit1 = row bit1
            B[g] = merge_red(b01, b23, 2, lane);
        }

        // Level mask4: lane bit2 = quad bit0
        const float A40 = merge_red(A[0], A[1], 4, lane);
        const float A41 = merge_red(A[2], A[3], 4, lane);
        const float B40 = merge_red(B[0], B[1], 4, lane);
        const float B41 = merge_red(B[2], B[3], 4, lane);
        // Level mask8: lane bit3 = quad bit1 -> row = lane & 15
        const float A16 = merge_red(A40, A41, 8, lane);
        const float B16 = merge_red(B40, B41, 8, lane);
        // Level mask16: lane bit4 = param (0 = a, 1 = b)
        const float fin0 = merge_red(A16, B16, 16, lane);
        // Complete the 64-lane sum across lane bit5 (same value both sides)
        const float fin = fin0 + __shfl_xor(fin0, 32, 64);
        // Pair a/b into every lane
        const float oth = __shfl_xor(fin, 16, 64);
        const float spa = (lane & 16) ? oth : fin;   // pa(rowbase + (lane&15))
        const float spb = (lane & 16) ? fin : oth;   // pb(rowbase + (lane&15))

        // ---- Epilogue, once per tile; lane l handles row rowbase+(l&15) ----
        const float a = softplus_f(spa + ba_s);
        const float b = softplus_f(spb + bb_s);

        uint32_t t0 = 0u;
        uint32_t t1 = (uint32_t)(rowbase + (lane & 15));
        threefry2x32_k042(t0, t1);
        const uint32_t bits = t0 ^ t1;
        const float f = __uint_as_float((bits >> 9) | 0x3f800000u) - 1.0f;
        const float u = fmaxf(f, 1.17549435e-38f);

        const float p     = expf(logf(u) / b);       // u^(1/b) in (0,1]
        const float one_m = 1.0f - p;
        const float k     = expf(logf(one_m) / a);   // log(0)=-inf -> k=0
        const float z = fminf(fmaxf(fmaf(k, 1.2f, -0.1f), 0.0f), 1.0f);

        if (lane < 16) out[rowbase + lane] = z;
    }
}

extern "C" void kernel_launch(void* const* d_in, const int* in_sizes, int n_in,
                              void* d_out, int out_size, void* d_ws, size_t ws_size,
                              hipStream_t stream) {
    const float* x  = (const float*)d_in[0];
    const float* Wa = (const float*)d_in[1];
    const float* ba = (const float*)d_in[2];
    const float* Wb = (const float*)d_in[3];
    const float* bb = (const float*)d_in[4];
    float* out = (float*)d_out;

    const int nrows = in_sizes[0] / 512;   // 131072

    // 8192 tiles of 16 rows; 2048 blocks x 256 thr = 8192 waves (8/SIMD
    // requested; actual occupancy = VGPR-limited), 1 tile each + stride guard.
    const int block = 256;
    const int grid  = 2048;
    kuma_mask_kernel<<<grid, block, 0, stream>>>(x, Wa, ba, Wb, bb, out, nrows);
}